// Round 11
// baseline (526.433 us; speedup 1.0000x reference)
//
#include <hip/hip_runtime.h>
#include <math.h>

#define NN 50000
#define NE 800000
#define MPAD 50048   // 391 * 128
#define NB 196       // ceil(NN/256)

typedef __attribute__((ext_vector_type(8))) short bf16x8;
typedef __attribute__((ext_vector_type(8))) unsigned short u16x8;
typedef __attribute__((ext_vector_type(4))) float f32x4;

__device__ __forceinline__ float leaky(float x){ return x > 0.f ? x : 0.2f*x; }

__device__ __forceinline__ unsigned short f2bf(float f){
  unsigned int u = __float_as_uint(f);
  unsigned int r = (u + 0x7fffu + ((u >> 16) & 1u)) >> 16;
  return (unsigned short)r;
}
__device__ __forceinline__ float bf2f(unsigned short u){
  return __uint_as_float(((unsigned int)u) << 16);
}

// ---------------- fused prep: zero deg/AS/AD + convert all 3 W + convert ee->bf16 ----------------
#define PREP_TOTAL (NN*4 + 256*64 + 256*256 + 64*256)
__global__ void k_prep(int* __restrict__ deg,
                       float* __restrict__ AS0, float* __restrict__ AD0,
                       float* __restrict__ AS1, float* __restrict__ AD1,
                       float* __restrict__ AS2, float* __restrict__ AD2,
                       const float* __restrict__ W0, unsigned short* __restrict__ Wt0,
                       const float* __restrict__ W1, unsigned short* __restrict__ Wt1,
                       const float* __restrict__ W2, unsigned short* __restrict__ Wt2,
                       const float* __restrict__ ee, unsigned short* __restrict__ eeb){
  int stride = gridDim.x*blockDim.x;
  for (int i = blockIdx.x*blockDim.x + threadIdx.x; i < PREP_TOTAL; i += stride){
    if (i < NN*4){
      if (i < NN) deg[i] = 0;
      AS0[i]=0.f; AD0[i]=0.f;
      AS1[i]=0.f; AD1[i]=0.f;
      AS2[i]=0.f; AD2[i]=0.f;
    } else if (i < NN*4 + 256*64){
      int idx = i - NN*4;                 // Wt0[n][k], K=64, Ncols=256
      int n = idx >> 6, k = idx & 63;
      Wt0[idx] = f2bf(W0[(size_t)k*256 + n]);
    } else if (i < NN*4 + 256*64 + 256*256){
      int idx = i - (NN*4 + 256*64);      // Wt1[n][k], K=256, Ncols=256
      int n = idx >> 8, k = idx & 255;
      Wt1[idx] = f2bf(W1[(size_t)k*256 + n]);
    } else {
      int idx = i - (NN*4 + 256*64 + 256*256);  // Wt2[n][k], K=256, Ncols=64
      int n = idx >> 8, k = idx & 255;
      Wt2[idx] = f2bf(W2[(size_t)k*64 + n]);
    }
  }
  // streamed ee f32 -> bf16 (8 elements per iteration)
  for (long long j = blockIdx.x*blockDim.x + threadIdx.x; j < (long long)NE*8; j += stride){
    const float4* rp = reinterpret_cast<const float4*>(ee + j*8);
    float4 a = rp[0], b = rp[1];
    u16x8 o;
    o[0]=f2bf(a.x); o[1]=f2bf(a.y); o[2]=f2bf(a.z); o[3]=f2bf(a.w);
    o[4]=f2bf(b.x); o[5]=f2bf(b.y); o[6]=f2bf(b.z); o[7]=f2bf(b.w);
    *reinterpret_cast<u16x8*>(eeb + j*8) = o;
  }
}

// ---------------- CSR build ----------------
__global__ void k_hist(const int* __restrict__ col, int* __restrict__ deg){
  int e = blockIdx.x*blockDim.x + threadIdx.x;
  if (e < NE) atomicAdd(&deg[col[e]], 1);
}

__global__ void k_scan1(const int* __restrict__ deg, int* __restrict__ off,
                        int* __restrict__ bsum){
  __shared__ int ws[4];
  int t = threadIdx.x;
  int i = blockIdx.x*256 + t;
  int v = (i<NN)? deg[i] : 0;
  int lane = t & 63, w = t >> 6;
  int x = v;
  #pragma unroll
  for (int d=1; d<64; d<<=1){
    int y = __shfl_up(x, d, 64);
    if (lane >= d) x += y;
  }
  if (lane==63) ws[w] = x;
  __syncthreads();
  int woff = 0;
  #pragma unroll
  for (int k=0;k<3;++k) if (k < w) woff += ws[k];
  int incl = x + woff;
  if (i<NN) off[i] = incl - v;
  if (t==255) bsum[blockIdx.x] = incl;
}

__global__ void k_scan2(int* __restrict__ bsum, int* __restrict__ off){
  __shared__ int ws[4];
  int t = threadIdx.x;
  int v = (t<NB)? bsum[t] : 0;
  int lane = t & 63, w = t >> 6;
  int x = v;
  #pragma unroll
  for (int d=1; d<64; d<<=1){
    int y = __shfl_up(x, d, 64);
    if (lane >= d) x += y;
  }
  if (lane==63) ws[w] = x;
  __syncthreads();
  int woff = 0;
  #pragma unroll
  for (int k=0;k<3;++k) if (k < w) woff += ws[k];
  int incl = x + woff;
  if (t<NB) bsum[t] = incl - v;
  if (t==NB-1) off[NN] = incl;
}

__global__ void k_scan3(const int* __restrict__ bsum, int* __restrict__ off,
                        int* __restrict__ cursor){
  int i = blockIdx.x*256 + threadIdx.x;
  if (i<NN){
    int v = off[i] + bsum[blockIdx.x];
    off[i] = v;
    cursor[i] = v;
  }
}

__global__ void k_scatter(const int* __restrict__ row, const int* __restrict__ col,
                          int* __restrict__ cursor, int* __restrict__ esrc, int* __restrict__ eid){
  int e = blockIdx.x*blockDim.x + threadIdx.x;
  if (e < NE){
    int c = col[e];
    int pos = atomicAdd(&cursor[c], 1);
    esrc[pos] = row[e];
    eid[pos]  = e;
  }
}

// ---------------- scatter-mean of bf16 edge embeds (8 groups, 2x unrolled prefetch) ----------------
__global__ void k_premix(const float* __restrict__ node, const unsigned short* __restrict__ eeb,
                         const int* __restrict__ off, const int* __restrict__ eid,
                         unsigned short* __restrict__ Xb){
  int wid  = (int)((blockIdx.x*blockDim.x + threadIdx.x) >> 6);
  int lane = threadIdx.x & 63;
  if (wid >= NN) return;
  int g  = lane >> 3;           // 8 groups
  int l8 = lane & 7;            // covers cols l8*8..+7
  int s0 = off[wid], s1 = off[wid+1];

  float a[8];
  #pragma unroll
  for (int v=0;v<8;++v) a[v]=0.f;

  int p = s0 + g;
  for (; p + 8 < s1; p += 16){
    int e0 = eid[p];
    int e1 = eid[p+8];
    u16x8 h0 = *reinterpret_cast<const u16x8*>(eeb + (size_t)e0*64 + l8*8);
    u16x8 h1 = *reinterpret_cast<const u16x8*>(eeb + (size_t)e1*64 + l8*8);
    #pragma unroll
    for (int v=0;v<8;++v)
      a[v] += bf2f((unsigned short)h0[v]) + bf2f((unsigned short)h1[v]);
  }
  if (p < s1){
    int e0 = eid[p];
    u16x8 h0 = *reinterpret_cast<const u16x8*>(eeb + (size_t)e0*64 + l8*8);
    #pragma unroll
    for (int v=0;v<8;++v) a[v] += bf2f((unsigned short)h0[v]);
  }

  #pragma unroll
  for (int mk=8; mk<64; mk<<=1){
    #pragma unroll
    for (int v=0;v<8;++v) a[v] += __shfl_xor(a[v], mk, 64);
  }
  if (lane < 8){
    int dcnt = s1 - s0;
    float c = 1.f/(float)(dcnt > 1 ? dcnt : 1);
    const float4* np = reinterpret_cast<const float4*>(node + (size_t)wid*64 + l8*8);
    float4 n0 = np[0], n1 = np[1];
    float nv[8] = {n0.x,n0.y,n0.z,n0.w,n1.x,n1.y,n1.z,n1.w};
    u16x8 o;
    #pragma unroll
    for (int v=0;v<8;++v) o[v] = f2bf(nv[v] + a[v]*c);
    *reinterpret_cast<u16x8*>(Xb + (size_t)wid*64 + l8*8) = o;
  }
}

// ---------------- bf16 MFMA GEMM + fused attention-coefficient epilogue ----------------
template<int BN, int K, int HEADS>
__global__ __launch_bounds__(256)
void k_gemm_mfma(const unsigned short* __restrict__ A,
                 const unsigned short* __restrict__ Bt,
                 unsigned short* __restrict__ C,
                 const float* __restrict__ asrc, const float* __restrict__ adst,
                 float* __restrict__ AS, float* __restrict__ AD, int Nc){
  constexpr int BM = 128, BK = 32;
  constexpr int WNT = BN/32;
  __shared__ __align__(16) unsigned short As[BM*BK];
  __shared__ __align__(16) unsigned short Bs[BN*BK];
  const int tid  = threadIdx.x;
  const int lane = tid & 63;
  const int wid  = tid >> 6;
  const int wr   = wid >> 1, wc = wid & 1;
  const int bm   = blockIdx.y * BM, bn = blockIdx.x * BN;
  const int r    = lane >> 2, kq = lane & 3;

  f32x4 acc[4][WNT];
  #pragma unroll
  for (int i=0;i<4;++i)
    #pragma unroll
    for (int j=0;j<WNT;++j) acc[i][j] = (f32x4){0.f,0.f,0.f,0.f};

  for (int k0=0; k0<K; k0+=BK){
    #pragma unroll
    for (int i=0;i<2;++i){
      int arow = wid*32 + i*16 + r;
      __builtin_amdgcn_global_load_lds(
        (const __attribute__((address_space(1))) void*)(A + (size_t)(bm+arow)*K + k0 + kq*8),
        (__attribute__((address_space(3))) void*)&As[(wid*32 + i*16)*BK],
        16, 0, 0);
    }
    #pragma unroll
    for (int i=0;i<BN/64;++i){
      int brow = wid*(BN/4) + i*16 + r;
      __builtin_amdgcn_global_load_lds(
        (const __attribute__((address_space(1))) void*)(Bt + (size_t)(bn+brow)*K + k0 + kq*8),
        (__attribute__((address_space(3))) void*)&Bs[(wid*(BN/4) + i*16)*BK],
        16, 0, 0);
    }
    __syncthreads();

    bf16x8 af[4], bfr[WNT];
    #pragma unroll
    for (int mi=0; mi<4; ++mi)
      af[mi] = *reinterpret_cast<const bf16x8*>(&As[(wr*64 + mi*16 + (lane&15))*BK + (lane>>4)*8]);
    #pragma unroll
    for (int ni=0; ni<WNT; ++ni)
      bfr[ni] = *reinterpret_cast<const bf16x8*>(&Bs[(wc*(BN/2) + ni*16 + (lane&15))*BK + (lane>>4)*8]);
    #pragma unroll
    for (int mi=0; mi<4; ++mi)
      #pragma unroll
      for (int ni=0; ni<WNT; ++ni)
        acc[mi][ni] = __builtin_amdgcn_mfma_f32_16x16x32_bf16(af[mi], bfr[ni], acc[mi][ni], 0, 0, 0);
    __syncthreads();
  }

  const int head = (bn + wc*(BN/2)) >> 6;
  float av[WNT], dv[WNT];
  #pragma unroll
  for (int ni=0; ni<WNT; ++ni){
    int ccol = bn + wc*(BN/2) + ni*16 + (lane&15);
    av[ni] = asrc[ccol];
    dv[ni] = adst[ccol];
  }

  #pragma unroll
  for (int mi=0; mi<4; ++mi){
    #pragma unroll
    for (int ni=0; ni<WNT; ++ni){
      int ccol = bn + wc*(BN/2) + ni*16 + (lane&15);
      int rbase = bm + wr*64 + mi*16 + (lane>>4)*4;
      #pragma unroll
      for (int reg=0; reg<4; ++reg)
        C[(size_t)(rbase+reg)*Nc + ccol] = f2bf(acc[mi][ni][reg]);
    }
    float sp[4] = {0.f,0.f,0.f,0.f}, dp[4] = {0.f,0.f,0.f,0.f};
    #pragma unroll
    for (int ni=0; ni<WNT; ++ni)
      #pragma unroll
      for (int reg=0; reg<4; ++reg){
        sp[reg] += acc[mi][ni][reg]*av[ni];
        dp[reg] += acc[mi][ni][reg]*dv[ni];
      }
    #pragma unroll
    for (int reg=0; reg<4; ++reg)
      #pragma unroll
      for (int mk=1; mk<16; mk<<=1){
        sp[reg] += __shfl_xor(sp[reg], mk, 64);
        dp[reg] += __shfl_xor(dp[reg], mk, 64);
      }
    if ((lane & 15) == 0){
      int rr = bm + wr*64 + mi*16 + (lane>>4)*4;
      #pragma unroll
      for (int reg=0; reg<4; ++reg){
        atomicAdd(&AS[(size_t)(rr+reg)*HEADS + head], sp[reg]);
        atomicAdd(&AD[(size_t)(rr+reg)*HEADS + head], dp[reg]);
      }
    }
  }
}

// ---------------- fixed-ref softmax aggregation (2x unrolled prefetch) ----------------
template<int HEADS, bool OUT_BF16>
__global__ void k_agg(const unsigned short* __restrict__ Hb, const float* __restrict__ AS,
                      const float* __restrict__ AD, const int* __restrict__ off,
                      const int* __restrict__ esrc,
                      const float* __restrict__ bias, const float* __restrict__ gamma,
                      const float* __restrict__ beta, void* __restrict__ OutP){
  constexpr int D  = HEADS*64;
  constexpr int L  = (HEADS==4) ? 16 : 8;    // lanes per row
  constexpr int C  = D / L;                  // cols per lane (16 or 8)
  constexpr int NG = 64 / L;                 // groups (4 or 8)
  constexpr int NV = C / 8;                  // u16x8 loads per lane (2 or 1)
  int wid  = (int)((blockIdx.x*blockDim.x + threadIdx.x) >> 6);
  int lane = threadIdx.x & 63;
  if (wid >= NN) return;
  const int g    = lane / L;
  const int lrow = lane & (L-1);
  const int col0 = lrow * C;
  const int head = col0 >> 6;

  float ad    = AD[(size_t)wid*HEADS + head];
  float wself = leaky(AS[(size_t)wid*HEADS + head] + ad);
  int s0 = off[wid], s1 = off[wid+1];

  float psum = 0.f;
  float acc[C];
  #pragma unroll
  for (int v=0;v<C;++v) acc[v]=0.f;

  if (g == 0){
    psum = 1.f;   // self loop: exp(wself - wself) = 1
    const u16x8* hp = reinterpret_cast<const u16x8*>(Hb + (size_t)wid*D + col0);
    u16x8 hv[NV];
    #pragma unroll
    for (int q=0;q<NV;++q) hv[q] = hp[q];
    #pragma unroll
    for (int v=0;v<C;++v) acc[v] = bf2f((unsigned short)hv[v>>3][v&7]);
  }

  int p = s0 + g;
  for (; p + NG < s1; p += 2*NG){
    int src0 = esrc[p];
    int src1 = esrc[p+NG];
    float as0 = AS[(size_t)src0*HEADS + head];
    float as1 = AS[(size_t)src1*HEADS + head];
    const u16x8* hp0 = reinterpret_cast<const u16x8*>(Hb + (size_t)src0*D + col0);
    const u16x8* hp1 = reinterpret_cast<const u16x8*>(Hb + (size_t)src1*D + col0);
    u16x8 hv0[NV], hv1[NV];
    #pragma unroll
    for (int q=0;q<NV;++q){ hv0[q] = hp0[q]; hv1[q] = hp1[q]; }
    float pw0 = __expf(leaky(as0 + ad) - wself);
    float pw1 = __expf(leaky(as1 + ad) - wself);
    psum += pw0 + pw1;
    #pragma unroll
    for (int v=0;v<C;++v)
      acc[v] += pw0*bf2f((unsigned short)hv0[v>>3][v&7])
              + pw1*bf2f((unsigned short)hv1[v>>3][v&7]);
  }
  if (p < s1){
    int src = esrc[p];
    float w  = leaky(AS[(size_t)src*HEADS + head] + ad);
    float pw = __expf(w - wself);
    psum += pw;
    const u16x8* hp = reinterpret_cast<const u16x8*>(Hb + (size_t)src*D + col0);
    u16x8 hv[NV];
    #pragma unroll
    for (int q=0;q<NV;++q) hv[q] = hp[q];
    #pragma unroll
    for (int v=0;v<C;++v) acc[v] += pw*bf2f((unsigned short)hv[v>>3][v&7]);
  }

  #pragma unroll
  for (int mk=L; mk<64; mk<<=1){
    psum += __shfl_xor(psum, mk, 64);
    #pragma unroll
    for (int v=0;v<C;++v) acc[v] += __shfl_xor(acc[v], mk, 64);
  }

  float inv = 1.f/psum;
  float val[C];
  float s=0.f, s2=0.f;
  #pragma unroll
  for (int v=0;v<C;++v){
    val[v] = acc[v]*inv + bias[col0+v];
    s  += val[v];
    s2 += val[v]*val[v];
  }
  #pragma unroll
  for (int mk=1; mk<64; mk<<=1){
    s  += __shfl_xor(s,  mk, 64);
    s2 += __shfl_xor(s2, mk, 64);
  }
  float mean = s/(float)(64*C);
  float var  = s2/(float)(64*C) - mean*mean;
  float rstd = rsqrtf(var + 1e-5f);
  if (g == 0){
    if constexpr (OUT_BF16){
      u16x8 o[NV];
      #pragma unroll
      for (int v=0;v<C;++v){
        float y = (val[v]-mean)*rstd*gamma[col0+v] + beta[col0+v];
        y = (y > 0.f) ? y : expm1f(y);
        o[v>>3][v&7] = f2bf(y);
      }
      u16x8* op = reinterpret_cast<u16x8*>((unsigned short*)OutP + (size_t)wid*D + col0);
      #pragma unroll
      for (int q=0;q<NV;++q) op[q] = o[q];
    } else {
      float o[C];
      #pragma unroll
      for (int v=0;v<C;++v){
        float y = (val[v]-mean)*rstd*gamma[col0+v] + beta[col0+v];
        o[v] = (y > 0.f) ? y : expm1f(y);
      }
      float4* op = reinterpret_cast<float4*>((float*)OutP + (size_t)wid*D + col0);
      #pragma unroll
      for (int q=0;q<C/4;++q){
        float4 o4 = {o[q*4+0],o[q*4+1],o[q*4+2],o[q*4+3]};
        op[q] = o4;
      }
    }
  }
}

// ---------------- launcher ----------------
extern "C" void kernel_launch(void* const* d_in, const int* in_sizes, int n_in,
                              void* d_out, int out_size, void* d_ws, size_t ws_size,
                              hipStream_t stream) {
  const float* node  = (const float*)d_in[0];
  const int*   eidx  = (const int*)d_in[1];
  const float* ee    = (const float*)d_in[2];
  const float* W0    = (const float*)d_in[3];
  const float* asrc0 = (const float*)d_in[4];
  const float* adst0 = (const float*)d_in[5];
  const float* b0    = (const float*)d_in[6];
  const float* g0    = (const float*)d_in[7];
  const float* be0   = (const float*)d_in[8];
  const float* W1    = (const float*)d_in[9];
  const float* asrc1 = (const float*)d_in[10];
  const float* adst1 = (const float*)d_in[11];
  const float* b1    = (const float*)d_in[12];
  const float* g1    = (const float*)d_in[13];
  const float* be1   = (const float*)d_in[14];
  const float* W2    = (const float*)d_in[15];
  const float* asrc2 = (const float*)d_in[16];
  const float* adst2 = (const float*)d_in[17];
  const float* b2    = (const float*)d_in[18];
  const float* g2    = (const float*)d_in[19];
  const float* be2   = (const float*)d_in[20];

  const int* row = eidx;
  const int* col = eidx + NE;

  unsigned short* Hb  = (unsigned short*)d_ws;          // [MPAD][256] bf16
  unsigned short* Xb0 = Hb  + (size_t)MPAD*256;         // [MPAD][64]
  unsigned short* Xb  = Xb0 + (size_t)MPAD*64;          // [MPAD][256]
  unsigned short* Wt0 = Xb  + (size_t)MPAD*256;         // [256][64]
  unsigned short* Wt1 = Wt0 + 256*64;                   // [256][256]
  unsigned short* Wt2 = Wt1 + 256*256;                  // [64][256]
  float* AS0 = (float*)(Wt2 + 64*256);                  // [MPAD][4] each
  float* AD0 = AS0 + (size_t)MPAD*4;
  float* AS1 = AD0 + (size_t)MPAD*4;
  float* AD1 = AS1 + (size_t)MPAD*4;
  float* AS2 = AD1 + (size_t)MPAD*4;
  float* AD2 = AS2 + (size_t)MPAD*4;
  int* deg   = (int*)(AD2 + (size_t)MPAD*4);
  int* off   = deg + NN;                                // NN+1
  int* cursor= off + NN + 1;
  int* esrc  = cursor + NN;                             // NE
  int* eid   = esrc + NE;                               // NE
  int* bsum  = eid + NE;                                // NB
  unsigned short* eeb = (unsigned short*)(bsum + NB + 64);  // [NE][64] bf16

  float* out = (float*)d_out;

  k_prep<<<2048, 256, 0, stream>>>(deg, AS0, AD0, AS1, AD1, AS2, AD2,
                                   W0, Wt0, W1, Wt1, W2, Wt2, ee, eeb);
  k_hist<<<(NE+255)/256, 256, 0, stream>>>(col, deg);
  k_scan1<<<NB, 256, 0, stream>>>(deg, off, bsum);
  k_scan2<<<1, 256, 0, stream>>>(bsum, off);
  k_scan3<<<NB, 256, 0, stream>>>(bsum, off, cursor);
  k_scatter<<<(NE+255)/256, 256, 0, stream>>>(row, col, cursor, esrc, eid);

  int nwaveblk = (NN*64 + 255)/256;
  k_premix<<<nwaveblk, 256, 0, stream>>>(node, eeb, off, eid, Xb0);

  // ---- layer 0: K=64, heads=4, Nc=256 ----
  {
    dim3 g(256/128, MPAD/128);
    k_gemm_mfma<128,64,4><<<g, 256, 0, stream>>>(Xb0, Wt0, Hb, asrc0, adst0, AS0, AD0, 256);
    k_agg<4,true><<<nwaveblk, 256, 0, stream>>>(Hb, AS0, AD0, off, esrc, b0, g0, be0, Xb);
  }
  // ---- layer 1: K=256, heads=4, Nc=256 ----
  {
    dim3 g(256/128, MPAD/128);
    k_gemm_mfma<128,256,4><<<g, 256, 0, stream>>>(Xb, Wt1, Hb, asrc1, adst1, AS1, AD1, 256);
    k_agg<4,true><<<nwaveblk, 256, 0, stream>>>(Hb, AS1, AD1, off, esrc, b1, g1, be1, Xb);
  }
  // ---- layer 2: K=256, heads=1, Nc=64, concat=False ----
  {
    dim3 g(64/64, MPAD/128);
    k_gemm_mfma<64,256,1><<<g, 256, 0, stream>>>(Xb, Wt2, Hb, asrc2, adst2, AS2, AD2, 64);
    k_agg<1,false><<<nwaveblk, 256, 0, stream>>>(Hb, AS2, AD2, off, esrc, b2, g2, be2, out);
  }
}

// Round 12
// 481.016 us; speedup vs baseline: 1.0944x; 1.0944x over previous
//
#include <hip/hip_runtime.h>
#include <math.h>

#define NN 50000
#define NE 800000
#define MPAD 50048   // 391 * 128
#define NB 196       // ceil(NN/256)

typedef __attribute__((ext_vector_type(8))) short bf16x8;
typedef __attribute__((ext_vector_type(8))) unsigned short u16x8;
typedef __attribute__((ext_vector_type(4))) float f32x4;

__device__ __forceinline__ float leaky(float x){ return x > 0.f ? x : 0.2f*x; }

__device__ __forceinline__ unsigned short f2bf(float f){
  unsigned int u = __float_as_uint(f);
  unsigned int r = (u + 0x7fffu + ((u >> 16) & 1u)) >> 16;
  return (unsigned short)r;
}
__device__ __forceinline__ float bf2f(unsigned short u){
  return __uint_as_float(((unsigned int)u) << 16);
}

// ---------------- fused prep: zero deg/AS/AD + convert/transpose all 3 W ----------------
#define PREP_TOTAL (NN*4 + 256*64 + 256*256 + 64*256)
__global__ void k_prep(int* __restrict__ deg,
                       float* __restrict__ AS0, float* __restrict__ AD0,
                       float* __restrict__ AS1, float* __restrict__ AD1,
                       float* __restrict__ AS2, float* __restrict__ AD2,
                       const float* __restrict__ W0, unsigned short* __restrict__ Wt0,
                       const float* __restrict__ W1, unsigned short* __restrict__ Wt1,
                       const float* __restrict__ W2, unsigned short* __restrict__ Wt2){
  for (int i = blockIdx.x*blockDim.x + threadIdx.x; i < PREP_TOTAL; i += gridDim.x*blockDim.x){
    if (i < NN*4){
      if (i < NN) deg[i] = 0;
      AS0[i]=0.f; AD0[i]=0.f;
      AS1[i]=0.f; AD1[i]=0.f;
      AS2[i]=0.f; AD2[i]=0.f;
    } else if (i < NN*4 + 256*64){
      int idx = i - NN*4;                 // Wt0[n][k], K=64, Ncols=256
      int n = idx >> 6, k = idx & 63;
      Wt0[idx] = f2bf(W0[(size_t)k*256 + n]);
    } else if (i < NN*4 + 256*64 + 256*256){
      int idx = i - (NN*4 + 256*64);      // Wt1[n][k], K=256, Ncols=256
      int n = idx >> 8, k = idx & 255;
      Wt1[idx] = f2bf(W1[(size_t)k*256 + n]);
    } else {
      int idx = i - (NN*4 + 256*64 + 256*256);  // Wt2[n][k], K=256, Ncols=64
      int n = idx >> 8, k = idx & 255;
      Wt2[idx] = f2bf(W2[(size_t)k*64 + n]);
    }
  }
}

// ---------------- CSR build ----------------
__global__ void k_hist(const int* __restrict__ col, int* __restrict__ deg){
  int e = blockIdx.x*blockDim.x + threadIdx.x;
  if (e < NE) atomicAdd(&deg[col[e]], 1);
}

__global__ void k_scan1(const int* __restrict__ deg, int* __restrict__ off,
                        int* __restrict__ bsum){
  __shared__ int ws[4];
  int t = threadIdx.x;
  int i = blockIdx.x*256 + t;
  int v = (i<NN)? deg[i] : 0;
  int lane = t & 63, w = t >> 6;
  int x = v;
  #pragma unroll
  for (int d=1; d<64; d<<=1){
    int y = __shfl_up(x, d, 64);
    if (lane >= d) x += y;
  }
  if (lane==63) ws[w] = x;
  __syncthreads();
  int woff = 0;
  #pragma unroll
  for (int k=0;k<3;++k) if (k < w) woff += ws[k];
  int incl = x + woff;
  if (i<NN) off[i] = incl - v;
  if (t==255) bsum[blockIdx.x] = incl;
}

__global__ void k_scan2(int* __restrict__ bsum, int* __restrict__ off){
  __shared__ int ws[4];
  int t = threadIdx.x;
  int v = (t<NB)? bsum[t] : 0;
  int lane = t & 63, w = t >> 6;
  int x = v;
  #pragma unroll
  for (int d=1; d<64; d<<=1){
    int y = __shfl_up(x, d, 64);
    if (lane >= d) x += y;
  }
  if (lane==63) ws[w] = x;
  __syncthreads();
  int woff = 0;
  #pragma unroll
  for (int k=0;k<3;++k) if (k < w) woff += ws[k];
  int incl = x + woff;
  if (t<NB) bsum[t] = incl - v;
  if (t==NB-1) off[NN] = incl;
}

__global__ void k_scan3(const int* __restrict__ bsum, int* __restrict__ off,
                        int* __restrict__ cursor){
  int i = blockIdx.x*256 + threadIdx.x;
  if (i<NN){
    int v = off[i] + bsum[blockIdx.x];
    off[i] = v;
    cursor[i] = v;
  }
}

__global__ void k_scatter(const int* __restrict__ row, const int* __restrict__ col,
                          int* __restrict__ cursor, int* __restrict__ esrc, int* __restrict__ eid){
  int e = blockIdx.x*blockDim.x + threadIdx.x;
  if (e < NE){
    int c = col[e];
    int pos = atomicAdd(&cursor[c], 1);
    esrc[pos] = row[e];
    eid[pos]  = e;
  }
}

// ---------------- scatter-mean of edge embeds (8 groups, 2x unrolled prefetch) ----------------
__global__ void k_premix(const float* __restrict__ node, const float* __restrict__ ee,
                         const int* __restrict__ off, const int* __restrict__ eid,
                         unsigned short* __restrict__ Xb){
  int wid  = (int)((blockIdx.x*blockDim.x + threadIdx.x) >> 6);
  int lane = threadIdx.x & 63;
  if (wid >= NN) return;
  int g  = lane >> 3;           // 8 groups
  int l8 = lane & 7;            // covers cols l8*8..+7
  int s0 = off[wid], s1 = off[wid+1];

  float a[8];
  #pragma unroll
  for (int v=0;v<8;++v) a[v]=0.f;

  int p = s0 + g;
  for (; p + 8 < s1; p += 16){
    int e0 = eid[p];
    int e1 = eid[p+8];
    const float4* r0 = reinterpret_cast<const float4*>(ee + (size_t)e0*64 + l8*8);
    const float4* r1 = reinterpret_cast<const float4*>(ee + (size_t)e1*64 + l8*8);
    float4 h00 = r0[0], h01 = r0[1];
    float4 h10 = r1[0], h11 = r1[1];
    a[0]+=h00.x+h10.x; a[1]+=h00.y+h10.y; a[2]+=h00.z+h10.z; a[3]+=h00.w+h10.w;
    a[4]+=h01.x+h11.x; a[5]+=h01.y+h11.y; a[6]+=h01.z+h11.z; a[7]+=h01.w+h11.w;
  }
  if (p < s1){
    int e0 = eid[p];
    const float4* r0 = reinterpret_cast<const float4*>(ee + (size_t)e0*64 + l8*8);
    float4 h00 = r0[0], h01 = r0[1];
    a[0]+=h00.x; a[1]+=h00.y; a[2]+=h00.z; a[3]+=h00.w;
    a[4]+=h01.x; a[5]+=h01.y; a[6]+=h01.z; a[7]+=h01.w;
  }

  #pragma unroll
  for (int mk=8; mk<64; mk<<=1){
    #pragma unroll
    for (int v=0;v<8;++v) a[v] += __shfl_xor(a[v], mk, 64);
  }
  if (lane < 8){
    int dcnt = s1 - s0;
    float c = 1.f/(float)(dcnt > 1 ? dcnt : 1);
    const float4* np = reinterpret_cast<const float4*>(node + (size_t)wid*64 + l8*8);
    float4 n0 = np[0], n1 = np[1];
    float nv[8] = {n0.x,n0.y,n0.z,n0.w,n1.x,n1.y,n1.z,n1.w};
    u16x8 o;
    #pragma unroll
    for (int v=0;v<8;++v) o[v] = f2bf(nv[v] + a[v]*c);
    *reinterpret_cast<u16x8*>(Xb + (size_t)wid*64 + l8*8) = o;
  }
}

// ---------------- bf16 MFMA GEMM + fused attention-coefficient epilogue ----------------
template<int BN, int K, int HEADS>
__global__ __launch_bounds__(256)
void k_gemm_mfma(const unsigned short* __restrict__ A,
                 const unsigned short* __restrict__ Bt,
                 unsigned short* __restrict__ C,
                 const float* __restrict__ asrc, const float* __restrict__ adst,
                 float* __restrict__ AS, float* __restrict__ AD, int Nc){
  constexpr int BM = 128, BK = 32;
  constexpr int WNT = BN/32;
  __shared__ __align__(16) unsigned short As[BM*BK];
  __shared__ __align__(16) unsigned short Bs[BN*BK];
  const int tid  = threadIdx.x;
  const int lane = tid & 63;
  const int wid  = tid >> 6;
  const int wr   = wid >> 1, wc = wid & 1;
  const int bm   = blockIdx.y * BM, bn = blockIdx.x * BN;
  const int r    = lane >> 2, kq = lane & 3;

  f32x4 acc[4][WNT];
  #pragma unroll
  for (int i=0;i<4;++i)
    #pragma unroll
    for (int j=0;j<WNT;++j) acc[i][j] = (f32x4){0.f,0.f,0.f,0.f};

  for (int k0=0; k0<K; k0+=BK){
    #pragma unroll
    for (int i=0;i<2;++i){
      int arow = wid*32 + i*16 + r;
      __builtin_amdgcn_global_load_lds(
        (const __attribute__((address_space(1))) void*)(A + (size_t)(bm+arow)*K + k0 + kq*8),
        (__attribute__((address_space(3))) void*)&As[(wid*32 + i*16)*BK],
        16, 0, 0);
    }
    #pragma unroll
    for (int i=0;i<BN/64;++i){
      int brow = wid*(BN/4) + i*16 + r;
      __builtin_amdgcn_global_load_lds(
        (const __attribute__((address_space(1))) void*)(Bt + (size_t)(bn+brow)*K + k0 + kq*8),
        (__attribute__((address_space(3))) void*)&Bs[(wid*(BN/4) + i*16)*BK],
        16, 0, 0);
    }
    __syncthreads();

    bf16x8 af[4], bfr[WNT];
    #pragma unroll
    for (int mi=0; mi<4; ++mi)
      af[mi] = *reinterpret_cast<const bf16x8*>(&As[(wr*64 + mi*16 + (lane&15))*BK + (lane>>4)*8]);
    #pragma unroll
    for (int ni=0; ni<WNT; ++ni)
      bfr[ni] = *reinterpret_cast<const bf16x8*>(&Bs[(wc*(BN/2) + ni*16 + (lane&15))*BK + (lane>>4)*8]);
    #pragma unroll
    for (int mi=0; mi<4; ++mi)
      #pragma unroll
      for (int ni=0; ni<WNT; ++ni)
        acc[mi][ni] = __builtin_amdgcn_mfma_f32_16x16x32_bf16(af[mi], bfr[ni], acc[mi][ni], 0, 0, 0);
    __syncthreads();
  }

  const int head = (bn + wc*(BN/2)) >> 6;
  float av[WNT], dv[WNT];
  #pragma unroll
  for (int ni=0; ni<WNT; ++ni){
    int ccol = bn + wc*(BN/2) + ni*16 + (lane&15);
    av[ni] = asrc[ccol];
    dv[ni] = adst[ccol];
  }

  #pragma unroll
  for (int mi=0; mi<4; ++mi){
    #pragma unroll
    for (int ni=0; ni<WNT; ++ni){
      int ccol = bn + wc*(BN/2) + ni*16 + (lane&15);
      int rbase = bm + wr*64 + mi*16 + (lane>>4)*4;
      #pragma unroll
      for (int reg=0; reg<4; ++reg)
        C[(size_t)(rbase+reg)*Nc + ccol] = f2bf(acc[mi][ni][reg]);
    }
    float sp[4] = {0.f,0.f,0.f,0.f}, dp[4] = {0.f,0.f,0.f,0.f};
    #pragma unroll
    for (int ni=0; ni<WNT; ++ni)
      #pragma unroll
      for (int reg=0; reg<4; ++reg){
        sp[reg] += acc[mi][ni][reg]*av[ni];
        dp[reg] += acc[mi][ni][reg]*dv[ni];
      }
    #pragma unroll
    for (int reg=0; reg<4; ++reg)
      #pragma unroll
      for (int mk=1; mk<16; mk<<=1){
        sp[reg] += __shfl_xor(sp[reg], mk, 64);
        dp[reg] += __shfl_xor(dp[reg], mk, 64);
      }
    if ((lane & 15) == 0){
      int rr = bm + wr*64 + mi*16 + (lane>>4)*4;
      #pragma unroll
      for (int reg=0; reg<4; ++reg){
        atomicAdd(&AS[(size_t)(rr+reg)*HEADS + head], sp[reg]);
        atomicAdd(&AD[(size_t)(rr+reg)*HEADS + head], dp[reg]);
      }
    }
  }
}

// ---------------- fixed-ref softmax aggregation (2x unrolled prefetch) ----------------
template<int HEADS, bool OUT_BF16>
__global__ void k_agg(const unsigned short* __restrict__ Hb, const float* __restrict__ AS,
                      const float* __restrict__ AD, const int* __restrict__ off,
                      const int* __restrict__ esrc,
                      const float* __restrict__ bias, const float* __restrict__ gamma,
                      const float* __restrict__ beta, void* __restrict__ OutP){
  constexpr int D  = HEADS*64;
  constexpr int L  = (HEADS==4) ? 16 : 8;    // lanes per row
  constexpr int C  = D / L;                  // cols per lane (16 or 8)
  constexpr int NG = 64 / L;                 // groups (4 or 8)
  constexpr int NV = C / 8;                  // u16x8 loads per lane (2 or 1)
  int wid  = (int)((blockIdx.x*blockDim.x + threadIdx.x) >> 6);
  int lane = threadIdx.x & 63;
  if (wid >= NN) return;
  const int g    = lane / L;
  const int lrow = lane & (L-1);
  const int col0 = lrow * C;
  const int head = col0 >> 6;

  float ad    = AD[(size_t)wid*HEADS + head];
  float wself = leaky(AS[(size_t)wid*HEADS + head] + ad);
  int s0 = off[wid], s1 = off[wid+1];

  float psum = 0.f;
  float acc[C];
  #pragma unroll
  for (int v=0;v<C;++v) acc[v]=0.f;

  if (g == 0){
    psum = 1.f;   // self loop: exp(wself - wself) = 1
    const u16x8* hp = reinterpret_cast<const u16x8*>(Hb + (size_t)wid*D + col0);
    u16x8 hv[NV];
    #pragma unroll
    for (int q=0;q<NV;++q) hv[q] = hp[q];
    #pragma unroll
    for (int v=0;v<C;++v) acc[v] = bf2f((unsigned short)hv[v>>3][v&7]);
  }

  int p = s0 + g;
  for (; p + NG < s1; p += 2*NG){
    int src0 = esrc[p];
    int src1 = esrc[p+NG];
    float as0 = AS[(size_t)src0*HEADS + head];
    float as1 = AS[(size_t)src1*HEADS + head];
    const u16x8* hp0 = reinterpret_cast<const u16x8*>(Hb + (size_t)src0*D + col0);
    const u16x8* hp1 = reinterpret_cast<const u16x8*>(Hb + (size_t)src1*D + col0);
    u16x8 hv0[NV], hv1[NV];
    #pragma unroll
    for (int q=0;q<NV;++q){ hv0[q] = hp0[q]; hv1[q] = hp1[q]; }
    float pw0 = __expf(leaky(as0 + ad) - wself);
    float pw1 = __expf(leaky(as1 + ad) - wself);
    psum += pw0 + pw1;
    #pragma unroll
    for (int v=0;v<C;++v)
      acc[v] += pw0*bf2f((unsigned short)hv0[v>>3][v&7])
              + pw1*bf2f((unsigned short)hv1[v>>3][v&7]);
  }
  if (p < s1){
    int src = esrc[p];
    float w  = leaky(AS[(size_t)src*HEADS + head] + ad);
    float pw = __expf(w - wself);
    psum += pw;
    const u16x8* hp = reinterpret_cast<const u16x8*>(Hb + (size_t)src*D + col0);
    u16x8 hv[NV];
    #pragma unroll
    for (int q=0;q<NV;++q) hv[q] = hp[q];
    #pragma unroll
    for (int v=0;v<C;++v) acc[v] += pw*bf2f((unsigned short)hv[v>>3][v&7]);
  }

  #pragma unroll
  for (int mk=L; mk<64; mk<<=1){
    psum += __shfl_xor(psum, mk, 64);
    #pragma unroll
    for (int v=0;v<C;++v) acc[v] += __shfl_xor(acc[v], mk, 64);
  }

  float inv = 1.f/psum;
  float val[C];
  float s=0.f, s2=0.f;
  #pragma unroll
  for (int v=0;v<C;++v){
    val[v] = acc[v]*inv + bias[col0+v];
    s  += val[v];
    s2 += val[v]*val[v];
  }
  #pragma unroll
  for (int mk=1; mk<64; mk<<=1){
    s  += __shfl_xor(s,  mk, 64);
    s2 += __shfl_xor(s2, mk, 64);
  }
  float mean = s/(float)(64*C);
  float var  = s2/(float)(64*C) - mean*mean;
  float rstd = rsqrtf(var + 1e-5f);
  if (g == 0){
    if constexpr (OUT_BF16){
      u16x8 o[NV];
      #pragma unroll
      for (int v=0;v<C;++v){
        float y = (val[v]-mean)*rstd*gamma[col0+v] + beta[col0+v];
        y = (y > 0.f) ? y : expm1f(y);
        o[v>>3][v&7] = f2bf(y);
      }
      u16x8* op = reinterpret_cast<u16x8*>((unsigned short*)OutP + (size_t)wid*D + col0);
      #pragma unroll
      for (int q=0;q<NV;++q) op[q] = o[q];
    } else {
      float o[C];
      #pragma unroll
      for (int v=0;v<C;++v){
        float y = (val[v]-mean)*rstd*gamma[col0+v] + beta[col0+v];
        o[v] = (y > 0.f) ? y : expm1f(y);
      }
      float4* op = reinterpret_cast<float4*>((float*)OutP + (size_t)wid*D + col0);
      #pragma unroll
      for (int q=0;q<C/4;++q){
        float4 o4 = {o[q*4+0],o[q*4+1],o[q*4+2],o[q*4+3]};
        op[q] = o4;
      }
    }
  }
}

// ---------------- launcher ----------------
extern "C" void kernel_launch(void* const* d_in, const int* in_sizes, int n_in,
                              void* d_out, int out_size, void* d_ws, size_t ws_size,
                              hipStream_t stream) {
  const float* node  = (const float*)d_in[0];
  const int*   eidx  = (const int*)d_in[1];
  const float* ee    = (const float*)d_in[2];
  const float* W0    = (const float*)d_in[3];
  const float* asrc0 = (const float*)d_in[4];
  const float* adst0 = (const float*)d_in[5];
  const float* b0    = (const float*)d_in[6];
  const float* g0    = (const float*)d_in[7];
  const float* be0   = (const float*)d_in[8];
  const float* W1    = (const float*)d_in[9];
  const float* asrc1 = (const float*)d_in[10];
  const float* adst1 = (const float*)d_in[11];
  const float* b1    = (const float*)d_in[12];
  const float* g1    = (const float*)d_in[13];
  const float* be1   = (const float*)d_in[14];
  const float* W2    = (const float*)d_in[15];
  const float* asrc2 = (const float*)d_in[16];
  const float* adst2 = (const float*)d_in[17];
  const float* b2    = (const float*)d_in[18];
  const float* g2    = (const float*)d_in[19];
  const float* be2   = (const float*)d_in[20];

  const int* row = eidx;
  const int* col = eidx + NE;

  unsigned short* Hb  = (unsigned short*)d_ws;          // [MPAD][256] bf16
  unsigned short* Xb0 = Hb  + (size_t)MPAD*256;         // [MPAD][64]
  unsigned short* Xb  = Xb0 + (size_t)MPAD*64;          // [MPAD][256]
  unsigned short* Wt0 = Xb  + (size_t)MPAD*256;         // [256][64]
  unsigned short* Wt1 = Wt0 + 256*64;                   // [256][256]
  unsigned short* Wt2 = Wt1 + 256*256;                  // [64][256]
  float* AS0 = (float*)(Wt2 + 64*256);                  // [MPAD][4] each
  float* AD0 = AS0 + (size_t)MPAD*4;
  float* AS1 = AD0 + (size_t)MPAD*4;
  float* AD1 = AS1 + (size_t)MPAD*4;
  float* AS2 = AD1 + (size_t)MPAD*4;
  float* AD2 = AS2 + (size_t)MPAD*4;
  int* deg   = (int*)(AD2 + (size_t)MPAD*4);
  int* off   = deg + NN;                                // NN+1
  int* cursor= off + NN + 1;
  int* esrc  = cursor + NN;                             // NE
  int* eid   = esrc + NE;                               // NE
  int* bsum  = eid + NE;                                // NB

  float* out = (float*)d_out;

  k_prep<<<512, 256, 0, stream>>>(deg, AS0, AD0, AS1, AD1, AS2, AD2,
                                  W0, Wt0, W1, Wt1, W2, Wt2);
  k_hist<<<(NE+255)/256, 256, 0, stream>>>(col, deg);
  k_scan1<<<NB, 256, 0, stream>>>(deg, off, bsum);
  k_scan2<<<1, 256, 0, stream>>>(bsum, off);
  k_scan3<<<NB, 256, 0, stream>>>(bsum, off, cursor);
  k_scatter<<<(NE+255)/256, 256, 0, stream>>>(row, col, cursor, esrc, eid);

  int nwaveblk = (NN*64 + 255)/256;
  k_premix<<<nwaveblk, 256, 0, stream>>>(node, ee, off, eid, Xb0);

  // ---- layer 0: K=64, heads=4, Nc=256 ----
  {
    dim3 g(256/128, MPAD/128);
    k_gemm_mfma<128,64,4><<<g, 256, 0, stream>>>(Xb0, Wt0, Hb, asrc0, adst0, AS0, AD0, 256);
    k_agg<4,true><<<nwaveblk, 256, 0, stream>>>(Hb, AS0, AD0, off, esrc, b0, g0, be0, Xb);
  }
  // ---- layer 1: K=256, heads=4, Nc=256 ----
  {
    dim3 g(256/128, MPAD/128);
    k_gemm_mfma<128,256,4><<<g, 256, 0, stream>>>(Xb, Wt1, Hb, asrc1, adst1, AS1, AD1, 256);
    k_agg<4,true><<<nwaveblk, 256, 0, stream>>>(Hb, AS1, AD1, off, esrc, b1, g1, be1, Xb);
  }
  // ---- layer 2: K=256, heads=1, Nc=64, concat=False ----
  {
    dim3 g(64/64, MPAD/128);
    k_gemm_mfma<64,256,1><<<g, 256, 0, stream>>>(Xb, Wt2, Hb, asrc2, adst2, AS2, AD2, 64);
    k_agg<1,false><<<nwaveblk, 256, 0, stream>>>(Hb, AS2, AD2, off, esrc, b2, g2, be2, out);
  }
}